// Round 13
// baseline (194.527 us; speedup 1.0000x reference)
//
#include <hip/hip_runtime.h>
#include <hip/hip_bf16.h>
#include <cstddef>

// 3-layer tanh RNN (B=8192, T=80, D=32, H=64), fused, MFMA.
// SYSTOLIC LAYER PIPELINE, 4-STEP CHUNKS (R12) + PER-STEP ACCUMULATORS:
// all input-projection MFMA32s for the whole interval issue at interval top
// (hiding the batched LDS reads), so the MFMA pipe drains under the tanh
// bursts instead of serializing with them. Layer-2 LDS publish dropped
// (wave 2's output lives only in registers; nothing reads it).
//
// Block = 192 thr = 3 waves; wave wv = layer wv. Interval m (0..21): wave wv
// computes its layer for t = 4*(m-wv) .. +3 (when valid). 1 barrier/interval.
// Own recurrence register-carried via the K=16 D==B identity (R9/R11/R12
// verified): tanh'd packed D-tile IS the next step's B-operand.
// LDS ring hb[layer<2][t&7][batch][j] (stride 72): writer slots {4k..4k+3},
// downstream reader {4k-4..4k-1} -> disjoint mod 8.
//
// MFMA maps (verified R2-R12):
//   K=32 A: A[m=lane&15][k=8q+i]; B: B[k=8q+i][n=lane&15]  (q=lane>>4)
//   K=16 A: A[m=lane&15][k=4q+i]; B==D: D[row=4q+r][col=lane&15]
// tanh via exp2 (bias pre-scaled by 2*log2e) - numerics identical to R12.
// NOTE (calibration, R12 post-mortem): effective clock ~1.15 GHz on this
// broker part, not 2.4 -- all cycle budgets below use 1.15.

typedef __attribute__((ext_vector_type(8))) short s16x8;
typedef __attribute__((ext_vector_type(4))) short s16x4;
typedef __attribute__((ext_vector_type(4))) float fx4;

#define MFMA32(A, B, C) __builtin_amdgcn_mfma_f32_16x16x32_bf16((A), (B), (C), 0, 0, 0)
#define MFMA16(A, B, C) __builtin_amdgcn_mfma_f32_16x16x16bf16_1k((A), (B), (C), 0, 0, 0)

#if __has_builtin(__builtin_amdgcn_exp2f)
#define EXP2F(x) __builtin_amdgcn_exp2f(x)
#else
#define EXP2F(x) exp2f(x)
#endif
#if __has_builtin(__builtin_amdgcn_rcpf)
#define RCPF(x) __builtin_amdgcn_rcpf(x)
#else
#define RCPF(x) (1.0f / (x))
#endif

static constexpr float K2LOG2E = 2.8853900817779268f;  // 2*log2(e)

__device__ __forceinline__ short f2bf(float f) {  // RNE float->bf16 (weights, one-time)
  union { float f; unsigned u; } v; v.f = f;
  unsigned r = v.u + 0x7FFFu + ((v.u >> 16) & 1u);
  return (short)(r >> 16);
}
__device__ __forceinline__ float bf2f(short s) {
  union { unsigned u; float f; } v; v.u = ((unsigned)(unsigned short)s) << 16;
  return v.f;
}
__device__ __forceinline__ unsigned pk2bf(float a, float b) {  // v_cvt_pk_bf16_f32
  float2 t; t.x = a; t.y = b;
  union { __hip_bfloat162 h; unsigned u; } c;
  c.h = __float22bfloat162_rn(t);
  return c.u;
}

__device__ __forceinline__ s16x4 wfragA16(const float* W, int ncols, int row, int col0) {
  const float* p = W + row * ncols + col0;
  s16x4 r;
#pragma unroll
  for (int i = 0; i < 4; ++i) r[i] = f2bf(p[i]);
  return r;
}
__device__ __forceinline__ s16x8 wfragA32(const float* W, int ncols, int row, int col0) {
  const float* p = W + row * ncols + col0;
  s16x8 r;
#pragma unroll
  for (int i = 0; i < 8; ++i) r[i] = f2bf(p[i]);
  return r;
}

// tanh(acc + bias) (bias pre-scaled by 2*log2e) -> packed bf16 (K=16 B-frag piece).
__device__ __forceinline__ s16x4 tanh_pack(fx4 acc, const float* bs) {
  float h[4];
#pragma unroll
  for (int r = 0; r < 4; ++r) {
    float e = EXP2F(__builtin_fmaf(acc[r], K2LOG2E, bs[r]));
    h[r] = __builtin_fmaf(-2.f, RCPF(e + 1.f), 1.f);
  }
  union { unsigned u[2]; s16x4 v; } p;
  p.u[0] = pk2bf(h[0], h[1]);
  p.u[1] = pk2bf(h[2], h[3]);
  return p.v;
}

__global__ __launch_bounds__(192, 2) void rnn3_chunk4b(
    const float* __restrict__ x,
    const float* __restrict__ Wih0, const float* __restrict__ Whh0,
    const float* __restrict__ bih0, const float* __restrict__ bhh0,
    const float* __restrict__ Wih1, const float* __restrict__ Whh1,
    const float* __restrict__ bih1, const float* __restrict__ bhh1,
    const float* __restrict__ Wih2, const float* __restrict__ Whh2,
    const float* __restrict__ bih2, const float* __restrict__ bhh2,
    const float* __restrict__ Wfc, const float* __restrict__ bfc,
    float* __restrict__ out)
{
  __shared__ __align__(16) short hb[2][8][16][72];  // layers 0,1 only; 36864 B

  const int tid = threadIdx.x;
  const int wv  = __builtin_amdgcn_readfirstlane(tid >> 6);  // 0..2 == layer
  const int ln  = tid & 63;
  const int q   = ln >> 4;        // K=32 k-quad / K=16 row-quad
  const int m15 = ln & 15;
  const int bbase = (int)blockIdx.x * 16;

  // ---------- this wave's layer parameters ----------
  const float* Wih = (wv == 0) ? Wih0 : (wv == 1) ? Wih1 : Wih2;
  const float* Whh = (wv == 0) ? Whh0 : (wv == 1) ? Whh1 : Whh2;
  const float* bi  = (wv == 0) ? bih0 : (wv == 1) ? bih1 : bih2;
  const float* bh  = (wv == 0) ? bhh0 : (wv == 1) ? bhh1 : bhh2;
  const int kin = (wv == 0) ? 32 : 64;

  // ---------- weights (VGPR-resident) ----------
  s16x8 wiA[4], wiB[4];           // input projection, K=32
  s16x4 wh16[4][4];               // own recurrence, K=16 (state register-carried)
  const s16x8 z8 = {0, 0, 0, 0, 0, 0, 0, 0};
#pragma unroll
  for (int t4 = 0; t4 < 4; ++t4) {
    const int row = 16 * t4 + m15;
    wiA[t4] = wfragA32(Wih, kin, row, 8 * q);
    wiB[t4] = wv ? wfragA32(Wih, 64, row, 32 + 8 * q) : z8;   // layer 0: K=32 only
#pragma unroll
    for (int kf = 0; kf < 4; ++kf)
      wh16[t4][kf] = wfragA16(Whh, 64, row, 16 * kf + 4 * q);
  }

  // ---------- biases pre-scaled; lane's j = 16*t4 + 4*q + r ----------
  float bsc[4][4];
#pragma unroll
  for (int t4 = 0; t4 < 4; ++t4)
#pragma unroll
    for (int r = 0; r < 4; ++r) {
      const int j = 16 * t4 + 4 * q + r;
      bsc[t4][r] = (bi[j] + bh[j]) * K2LOG2E;
    }

  const fx4 z4 = {0.f, 0.f, 0.f, 0.f};
  const s16x4 z2 = {0, 0, 0, 0};
  s16x4 hf[4] = {z2, z2, z2, z2};   // own state h_wv(t-1), K=16 B-frags (regs)

  // ---------- wave-0 x buffer: 4 t's of this interval ----------
  const float* xr = x + (size_t)(bbase + m15) * (80 * 32) + 8 * q;
  fx4 xb0[4], xb1[4];
  if (wv == 0) {
#pragma unroll
    for (int jj = 0; jj < 4; ++jj) {          // preload t = 0..3
      xb0[jj] = *(const fx4*)(xr + jj * 32);
      xb1[jj] = *(const fx4*)(xr + jj * 32 + 4);
    }
  }

  for (int m = 0; m < 22; ++m) {
    const int lt0 = 4 * (m - wv);             // first t of this interval
    if (0 <= lt0 && lt0 <= 76) {              // wave-uniform
      // ---- interval top: gather all 4 inputs ----
      s16x8 inA[4], inB[4];
      if (wv == 0) {
#pragma unroll
        for (int jj = 0; jj < 4; ++jj) {
          union { unsigned u[4]; s16x8 v; } xp;
          xp.u[0] = pk2bf(xb0[jj][0], xb0[jj][1]);
          xp.u[1] = pk2bf(xb0[jj][2], xb0[jj][3]);
          xp.u[2] = pk2bf(xb1[jj][0], xb1[jj][1]);
          xp.u[3] = pk2bf(xb1[jj][2], xb1[jj][3]);
          inA[jj] = xp.v; inB[jj] = z8;
        }
        // refill for next interval; the loads drain at the barrier, once
#pragma unroll
        for (int jj = 0; jj < 4; ++jj) {
          const int tt = (lt0 + 4 + jj <= 79) ? lt0 + 4 + jj : 79;
          xb0[jj] = *(const fx4*)(xr + tt * 32);
          xb1[jj] = *(const fx4*)(xr + tt * 32 + 4);
        }
      } else {
#pragma unroll
        for (int jj = 0; jj < 4; ++jj) {
          const short* up = &hb[wv - 1][(lt0 + jj) & 7][m15][8 * q];
          inA[jj] = *(const s16x8*)(up);
          inB[jj] = *(const s16x8*)(up + 32);
        }
      }
      // ---- PRE-ISSUE all 4 steps' input GEMMs into per-step accumulators ----
      // These depend only on inA/inB (ready now), not on hf -> the MFMA pipe
      // gets a deep independent queue to drain under the tanh bursts below.
      fx4 acc[4][4];
#pragma unroll
      for (int jj = 0; jj < 4; ++jj)
#pragma unroll
        for (int t4 = 0; t4 < 4; ++t4) acc[jj][t4] = MFMA32(wiA[t4], inA[jj], z4);
      if (wv) {
#pragma unroll
        for (int jj = 0; jj < 4; ++jj)
#pragma unroll
          for (int t4 = 0; t4 < 4; ++t4)
            acc[jj][t4] = MFMA32(wiB[t4], inB[jj], acc[jj][t4]);
      }
      // ---- 4 sequential steps: recurrence MFMA16s + tanh only ----
#pragma unroll
      for (int jj = 0; jj < 4; ++jj) {
        const int st = (lt0 + jj) & 7;
#pragma unroll
        for (int kf = 0; kf < 4; ++kf)
#pragma unroll
          for (int t4 = 0; t4 < 4; ++t4)
            acc[jj][t4] = MFMA16(wh16[t4][kf], hf[kf], acc[jj][t4]);
        // tanh -> new own state (D==B identity); publish only layers 0,1
        short* wb = &hb[wv & 1][st][m15][4 * q];   // wv==2 never stores (guard below)
#pragma unroll
        for (int t4 = 0; t4 < 4; ++t4) {
          s16x4 hv = tanh_pack(acc[jj][t4], bsc[t4]);
          hf[t4] = hv;
          if (wv != 2) *(s16x4*)(wb + 16 * t4) = hv;
        }
      }
    }
    __syncthreads();                          // ONE barrier per 4-step interval
  }

  // ---------- FC head: wave 2's hf == h2(79), K=16 B-frag layout ----------
  if (wv == 2) {
    float sv = 0.f;
#pragma unroll
    for (int kf = 0; kf < 4; ++kf)
#pragma unroll
      for (int i = 0; i < 4; ++i)
        sv += bf2f(hf[kf][i]) * Wfc[16 * kf + 4 * q + i];
    sv += __shfl_xor(sv, 16, 64);
    sv += __shfl_xor(sv, 32, 64);
    if (ln < 16) out[bbase + ln] = sv + bfc[0];
  }
}

extern "C" void kernel_launch(void* const* d_in, const int* in_sizes, int n_in,
                              void* d_out, int out_size, void* d_ws, size_t ws_size,
                              hipStream_t stream) {
  const float* x    = (const float*)d_in[0];
  const float* Wih0 = (const float*)d_in[1];
  const float* Whh0 = (const float*)d_in[2];
  const float* bih0 = (const float*)d_in[3];
  const float* bhh0 = (const float*)d_in[4];
  const float* Wih1 = (const float*)d_in[5];
  const float* Whh1 = (const float*)d_in[6];
  const float* bih1 = (const float*)d_in[7];
  const float* bhh1 = (const float*)d_in[8];
  const float* Wih2 = (const float*)d_in[9];
  const float* Whh2 = (const float*)d_in[10];
  const float* bih2 = (const float*)d_in[11];
  const float* bhh2 = (const float*)d_in[12];
  const float* Wfc  = (const float*)d_in[13];
  const float* bfc  = (const float*)d_in[14];

  // 512 blocks x 192 thr (3 waves = 3 pipelined layers), 16 batch rows per block.
  rnn3_chunk4b<<<dim3(512), dim3(192), 0, stream>>>(
      x, Wih0, Whh0, bih0, bhh0, Wih1, Whh1, bih1, bhh1,
      Wih2, Whh2, bih2, bhh2, Wfc, bfc, (float*)d_out);
}